// Round 4
// baseline (312.906 us; speedup 1.0000x reference)
//
#include <hip/hip_runtime.h>
#include <math.h>

// out[b,s,d] = emb_table[x[b,s], d] + pe[s,d]
//   pe[s, 2i]   = sin(s * f_i),  pe[s, 2i+1] = cos(s * f_i),  f_i = 10000^(-2i/1024)
// D_M = 1024, B = 8, S = 4096, VOCAB = 50257 (fp32 table)

#define D_M   1024
#define SEQ   4096
#define BATCH 8

typedef float f4 __attribute__((ext_vector_type(4)));  // native clang vector: ok for nontemporal builtins

__global__ __launch_bounds__(256) void SinusoidalEmbedding_83030307766274_kernel(
    const int* __restrict__ x,
    const float* __restrict__ emb_table,
    float* __restrict__ out)
{
    const int s  = blockIdx.x;     // sequence position, [0, SEQ)
    const int d4 = threadIdx.x;    // float4 column index, [0, 256)

    // ---- row indices: block-uniform -> force scalar (SGPR base for gathers) ----
    int rows[BATCH];
#pragma unroll
    for (int b = 0; b < BATCH; ++b)
        rows[b] = __builtin_amdgcn_readfirstlane(x[b * SEQ + s]);

    // ---- issue all 8 gathers up-front (independent, in-flight under the trig) ----
    f4 v[BATCH];
#pragma unroll
    for (int b = 0; b < BATCH; ++b)
        v[b] = ((const f4*)(emb_table + (size_t)rows[b] * D_M))[d4];

    // ---- positional encoding, once per (s, d4), shared by all 8 batch rows ----
    // inv_freq(i) = 10000^(-2i/D) = exp2(i * c),  c = -2*log2(10000)/D
    // revolutions for v_sin/v_cos: r = fract(s * inv_freq / 2pi)
    const float c      = -2.0f * 13.28771237954945f / (float)D_M;
    const float inv2pi = 0.15915494309189535f;
    const float i0 = (float)(2 * d4);
    const float f0 = exp2f(i0 * c) * inv2pi;
    const float f1 = exp2f((i0 + 1.0f) * c) * inv2pi;
    const float sp = (float)s;

    float r0 = __builtin_amdgcn_fractf(sp * f0);
    float r1 = __builtin_amdgcn_fractf(sp * f1);
    f4 pe;
    pe.x = __builtin_amdgcn_sinf(r0);  // even col: sin
    pe.y = __builtin_amdgcn_cosf(r0);  // odd  col: cos
    pe.z = __builtin_amdgcn_sinf(r1);
    pe.w = __builtin_amdgcn_cosf(r1);

    // ---- add PE and stream out with non-temporal stores (don't pollute L2/L3;
    //      the gather stream needs the caches for duplicate-row absorption) ----
    f4* __restrict__ o4 = (f4*)out;
#pragma unroll
    for (int b = 0; b < BATCH; ++b) {
        f4 o = v[b] + pe;
        __builtin_nontemporal_store(o, &o4[((size_t)b * SEQ + s) * (D_M / 4) + d4]);
    }
}

extern "C" void kernel_launch(void* const* d_in, const int* in_sizes, int n_in,
                              void* d_out, int out_size, void* d_ws, size_t ws_size,
                              hipStream_t stream)
{
    const int*   x         = (const int*)d_in[0];     // [B, S] token ids (int32)
    const float* emb_table = (const float*)d_in[1];   // [VOCAB, D_M] fp32
    float*       out       = (float*)d_out;           // [B, S, D_M] fp32

    SinusoidalEmbedding_83030307766274_kernel<<<SEQ, 256, 0, stream>>>(x, emb_table, out);
}